// Round 1
// baseline (263.389 us; speedup 1.0000x reference)
//
#include <hip/hip_runtime.h>
#include <hip/hip_bf16.h>
#include <stdint.h>

// RSNN: T=256 steps, B=32, N_IN=256, N=2048.
// out = [3, T, B, N] fp32: zs | vs | z2s  (TBN elements each)
//
// Pipeline (all on `stream`, stream-ordered):
//   1. wt_convert: W_bern fp32 [k][n] -> Wt bf16 [n][k]   (ws +0, 8 MB)
//   2. in_gemm:    I = x @ W_in + b  (fp32, M=8192,K=256,N=2048) -> Ibuf
//   3. scan:       per-neuron serial v scan; writes zs, vs (fp32) and Z bf16 (ws +8MB, 32 MB)
//   4. bern_gemm:  Y = Z @ W_bern  (bf16 MFMA, M=8192,N=2048,K=2048) -> z2 region
//   5. gather_k:   z2[t,b,j] = Y[t,b,idx[t,j]]  in place (row via LDS)
//
// ws requirement: 40 MB minimum (Wt + Z). If ws >= 104 MB, I goes in ws too
// (separate buffer => restrict kernels, no store/load alias stalls); otherwise
// I is staged in the vs output region and overwritten in place by the scan.

#define T_STEPS 256
#define BATCH   32
#define NIN     256
#define NN      2048
#define BN_FLAT (BATCH * NN)            // 65536
#define TBN     (T_STEPS * BATCH * NN)  // 16777216
#define MROWS   (T_STEPS * BATCH)       // 8192

typedef __attribute__((ext_vector_type(4))) float fx4;
typedef __attribute__((ext_vector_type(4))) int   ix4;

__device__ __forceinline__ void gll16(const void* g, void* l) {
  typedef __attribute__((address_space(1))) void gvoid_t;
  typedef __attribute__((address_space(3))) void lvoid_t;
  __builtin_amdgcn_global_load_lds((gvoid_t*)(g), (lvoid_t*)(l), 16, 0, 0);
}

__device__ __forceinline__ void mfma16(fx4& d, ix4 a, ix4 b) {
  asm volatile("v_mfma_f32_16x16x32_bf16 %0, %1, %2, %0" : "+v"(d) : "v"(a), "v"(b));
}

// ---------------------------------------------------------------- kernel 1
__global__ __launch_bounds__(256) void wt_convert(const float* __restrict__ W,
                                                  __hip_bfloat16* __restrict__ Wt) {
  __shared__ float tile[32][33];
  const int k0 = blockIdx.y << 5, n0 = blockIdx.x << 5;
  const int tx = threadIdx.x, ty = threadIdx.y;
#pragma unroll
  for (int i = 0; i < 32; i += 8)
    tile[ty + i][tx] = W[(size_t)(k0 + ty + i) * NN + n0 + tx];
  __syncthreads();
#pragma unroll
  for (int i = 0; i < 32; i += 8)
    Wt[(size_t)(n0 + ty + i) * NN + k0 + tx] = __float2bfloat16(tile[tx][ty + i]);
}

// ---------------------------------------------------------------- kernel 2
// fp32 GEMM: I[8192][2048] = X[8192][256] @ Wi[256][2048] + bias
// 64x64 tile per block, 256 threads, 4x4 micro-tile, BK=16.
__global__ __launch_bounds__(256) void in_gemm(const float* __restrict__ X,
                                               const float* __restrict__ Wi,
                                               const float* __restrict__ bias,
                                               float* __restrict__ I) {
  __shared__ float As[16][68];  // As[k][m], padded: 272 B rows (16B-aligned, low conflict)
  __shared__ float Bs[16][64];  // Bs[k][n]
  const int tid = threadIdx.x;
  const int tx = tid & 15, ty = tid >> 4;
  const int m0 = blockIdx.x * 64, n0 = blockIdx.y * 64;
  float acc[4][4] = {};
  for (int k0 = 0; k0 < NIN; k0 += 16) {
#pragma unroll
    for (int it = 0; it < 4; ++it) {
      int r = (tid >> 4) + it * 16;
      As[tid & 15][r] = X[(size_t)(m0 + r) * NIN + k0 + (tid & 15)];
    }
#pragma unroll
    for (int it = 0; it < 4; ++it) {
      int kk = (tid >> 6) + it * 4;
      int c = tid & 63;
      Bs[kk][c] = Wi[(size_t)(k0 + kk) * NN + n0 + c];
    }
    __syncthreads();
#pragma unroll
    for (int kk = 0; kk < 16; ++kk) {
      fx4 a = *(const fx4*)&As[kk][ty * 4];
      fx4 b = *(const fx4*)&Bs[kk][tx * 4];
#pragma unroll
      for (int i = 0; i < 4; ++i)
#pragma unroll
        for (int j = 0; j < 4; ++j)
          acc[i][j] = fmaf(a[i], b[j], acc[i][j]);
    }
    __syncthreads();
  }
#pragma unroll
  for (int i = 0; i < 4; ++i) {
    int r = m0 + ty * 4 + i;
    fx4 res;
#pragma unroll
    for (int j = 0; j < 4; ++j) res[j] = acc[i][j] + bias[n0 + tx * 4 + j];
    *(fx4*)&I[(size_t)r * NN + n0 + tx * 4] = res;
  }
}

// ---------------------------------------------------------------- kernel 3
// Per-neuron serial scan over t. One thread per (b,n). Prefetch-unrolled x8.
// Matches numpy elementwise semantics: decay*v computed with separate
// mul+add (no fma contraction) so rounding matches the reference closely.
__device__ __forceinline__ void scan_body(float* zs, float* vsout,
                                          const float* I, __hip_bfloat16* Zb) {
  const int nid = blockIdx.x * 256 + threadIdx.x;  // 0..65535
  float v = 0.f;
  for (int t0 = 0; t0 < T_STEPS; t0 += 8) {
    float iin[8];
#pragma unroll
    for (int u = 0; u < 8; ++u)
      iin[u] = I[(size_t)(t0 + u) * BN_FLAT + nid];
#pragma unroll
    for (int u = 0; u < 8; ++u) {
      float nv = __fadd_rn(__fmul_rn(0.9048374180359595f, v), iin[u]);
      nv = fminf(fmaxf(nv, -1.0f), 1.01f);
      const bool sp = nv > 1.0f;        // == (new_v - THR) > 0 in fp32
      const float z = sp ? 1.0f : 0.0f;
      nv = sp ? -1.0f : nv;             // hard reset
      const size_t off = (size_t)(t0 + u) * BN_FLAT + nid;
      zs[off] = z;
      vsout[off] = nv;
      Zb[off] = __float2bfloat16(z);    // exact 0/1
      v = nv;
    }
  }
}

__global__ __launch_bounds__(256) void scan_sep(float* __restrict__ out,
                                                const float* __restrict__ I,
                                                __hip_bfloat16* __restrict__ Zb) {
  scan_body(out, out + (size_t)TBN, I, Zb);
}

__global__ __launch_bounds__(256) void scan_inp(float* out, __hip_bfloat16* Zb) {
  scan_body(out, out + (size_t)TBN, out + (size_t)TBN, Zb);  // I staged in vs region
}

// ---------------------------------------------------------------- kernel 4
// bf16 MFMA GEMM (m97 structure): Y[8192][2048] = Z[8192][2048] @ W[2048][2048]
// A = Z row-major bf16; B = Wt (W transposed) row-major bf16 so B-fragments
// are contiguous. 128x128 tile, BK=32, 4 waves (2x2), 16x16x32 MFMA.
__global__ __launch_bounds__(256) void bern_gemm(const __hip_bfloat16* __restrict__ Z,
                                                 const __hip_bfloat16* __restrict__ Wt,
                                                 float* __restrict__ Y) {
  __shared__ __align__(16) __hip_bfloat16 Asm[128 * 32];
  __shared__ __align__(16) __hip_bfloat16 Bsm[128 * 32];
  const int tid = threadIdx.x;
  const int lane = tid & 63;
  const int wid = tid >> 6;
  const int wr = wid >> 1, wc = wid & 1;
  const int m0 = blockIdx.x * 128, n0 = blockIdx.y * 128;

  fx4 acc[4][4] = {};

  // staging: per issue, 256 threads x 16B = 4KB = 64 rows of 64B. Two issues
  // per operand cover 128 rows. LDS dest is wave-uniform base + lane*16.
  const int trow = tid >> 2;
  const int tcol = (tid & 3) << 4;
  const char* gA = (const char*)Z + ((size_t)(m0 + trow) << 12) + tcol;
  const char* gB = (const char*)Wt + ((size_t)(n0 + trow) << 12) + tcol;
  char* lA = (char*)Asm + tid * 16;
  char* lB = (char*)Bsm + tid * 16;

  const ix4* Au = (const ix4*)Asm;  // 16B units; row = 4 units
  const ix4* Bu = (const ix4*)Bsm;
  const int abase = (wr * 64 + (lane & 15)) * 4 + (lane >> 4);
  const int bbase = (wc * 64 + (lane & 15)) * 4 + (lane >> 4);

  for (int ks = 0; ks < 64; ++ks) {
    gll16(gA, lA);
    gll16(gA + (size_t)64 * 4096, lA + 4096);
    gll16(gB, lB);
    gll16(gB + (size_t)64 * 4096, lB + 4096);
    gA += 64;  // advance 32 bf16 in k
    gB += 64;
    __syncthreads();  // compiler drains vmcnt before s_barrier

    ix4 af[4], bf[4];
#pragma unroll
    for (int i = 0; i < 4; ++i) af[i] = Au[abase + i * 64];
#pragma unroll
    for (int i = 0; i < 4; ++i) bf[i] = Bu[bbase + i * 64];
#pragma unroll
    for (int mf = 0; mf < 4; ++mf)
#pragma unroll
      for (int nf = 0; nf < 4; ++nf)
        mfma16(acc[mf][nf], af[mf], bf[nf]);
    __syncthreads();
  }

  asm volatile("s_nop 7\n\ts_nop 7");  // MFMA->VALU read insurance

  // C/D layout: col = lane&15, row = (lane>>4)*4 + reg  (m89-verified)
  const int crow = (lane >> 4) * 4;
  const int ccol = lane & 15;
#pragma unroll
  for (int mf = 0; mf < 4; ++mf)
#pragma unroll
    for (int nf = 0; nf < 4; ++nf)
#pragma unroll
      for (int j = 0; j < 4; ++j) {
        const int r = m0 + wr * 64 + mf * 16 + crow + j;
        const int c = n0 + wc * 64 + nf * 16 + ccol;
        Y[(size_t)r * NN + c] = acc[mf][nf][j];
      }
}

// ---------------------------------------------------------------- kernel 5
// In-place column gather: one block per (t,b) row. Row -> LDS, barrier,
// scatter-write. Safe in place because the full row is read before any write.
__global__ __launch_bounds__(256) void gather_k(float* __restrict__ Y,
                                                const int* __restrict__ ridx) {
  __shared__ __align__(16) float rowbuf[NN];
  const int tb = blockIdx.x;      // 0..8191
  const int t = tb >> 5;
  float* yrow = Y + (size_t)tb * NN;
  const int tid = threadIdx.x;
#pragma unroll
  for (int i = 0; i < 2; ++i) {
    int u = tid + i * 256;  // float4 units, 512 total
    ((fx4*)rowbuf)[u] = ((const fx4*)yrow)[u];
  }
  __syncthreads();
  const int* ir = ridx + t * NN;
#pragma unroll
  for (int i = 0; i < 8; ++i) {
    int j = tid + i * 256;
    yrow[j] = rowbuf[ir[j]];
  }
}

// ---------------------------------------------------------------- launcher
extern "C" void kernel_launch(void* const* d_in, const int* in_sizes, int n_in,
                              void* d_out, int out_size, void* d_ws, size_t ws_size,
                              hipStream_t stream) {
  const float* x      = (const float*)d_in[0];
  const float* W_in   = (const float*)d_in[1];
  const float* bias   = (const float*)d_in[2];
  const float* W_bern = (const float*)d_in[3];
  const int*   ridx   = (const int*)d_in[4];
  float* out = (float*)d_out;
  char* ws = (char*)d_ws;

  __hip_bfloat16* Wt = (__hip_bfloat16*)ws;                       // 8,388,608 B
  __hip_bfloat16* Zb = (__hip_bfloat16*)(ws + (size_t)8388608);   // 33,554,432 B
  const size_t offI = 41943040;                                   // I: 67,108,864 B
  const bool sep = ws_size >= (size_t)109051904;
  float* Ibuf = sep ? (float*)(ws + offI) : (out + (size_t)TBN);

  wt_convert<<<dim3(64, 64), dim3(32, 8), 0, stream>>>(W_bern, Wt);
  in_gemm<<<dim3(128, 32), dim3(256), 0, stream>>>(x, W_in, bias, Ibuf);
  if (sep)
    scan_sep<<<dim3(256), dim3(256), 0, stream>>>(out, Ibuf, Zb);
  else
    scan_inp<<<dim3(256), dim3(256), 0, stream>>>(out, Zb);
  bern_gemm<<<dim3(64, 16), dim3(256), 0, stream>>>(Zb, Wt, out + (size_t)2 * TBN);
  gather_k<<<dim3(8192), dim3(256), 0, stream>>>(out + (size_t)2 * TBN, ridx);
}

// Round 2
// 252.320 us; speedup vs baseline: 1.0439x; 1.0439x over previous
//
#include <hip/hip_runtime.h>
#include <hip/hip_bf16.h>
#include <stdint.h>

// RSNN: T=256 steps, B=32, N_IN=256, N=2048.
// out = [3, T, B, N] fp32: zs | vs | z2s  (TBN elements each)
//
// Pipeline (all on `stream`, stream-ordered):
//   0. xt_k:       X fp32 [M][K] -> Xt [K][M]  (borrows zs out-region, pre-scan)
//   1. wt_convert: W_bern fp32 [k][n] -> Wt bf16 [n][k]   (ws +0, 8 MB)
//   2. in_gemm:    I = x @ W_in + b  (fp32, M=8192,K=256,N=2048) -> Ibuf
//                  256x128 tile, 16x8 micro, gll16 staging both operands
//   3. scan:       per-neuron serial v scan; writes zs, vs (fp32) and Z bf16 (ws +8MB)
//   4. bern_gemm:  Y = Z @ W_bern  (bf16 MFMA, M=8192,N=2048,K=2048) -> z2 region
//   5. gather_k:   z2[t,b,j] = Y[t,b,idx[t,j]]  in place (row via LDS)

#define T_STEPS 256
#define BATCH   32
#define NIN     256
#define NN      2048
#define BN_FLAT (BATCH * NN)            // 65536
#define TBN     (T_STEPS * BATCH * NN)  // 16777216
#define MROWS   (T_STEPS * BATCH)       // 8192

typedef __attribute__((ext_vector_type(4))) float fx4;
typedef __attribute__((ext_vector_type(4))) int   ix4;

__device__ __forceinline__ void gll16(const void* g, void* l) {
  typedef __attribute__((address_space(1))) void gvoid_t;
  typedef __attribute__((address_space(3))) void lvoid_t;
  __builtin_amdgcn_global_load_lds((gvoid_t*)(g), (lvoid_t*)(l), 16, 0, 0);
}

__device__ __forceinline__ void mfma16(fx4& d, ix4 a, ix4 b) {
  asm volatile("v_mfma_f32_16x16x32_bf16 %0, %1, %2, %0" : "+v"(d) : "v"(a), "v"(b));
}

// ---------------------------------------------------------------- kernel 0
// X [8192][256] -> Xt [256][8192]
__global__ __launch_bounds__(256) void xt_k(const float* __restrict__ X,
                                            float* __restrict__ Xt) {
  __shared__ float tile[32][33];
  const int m0 = blockIdx.x << 5, k0 = blockIdx.y << 5;
  const int tx = threadIdx.x, ty = threadIdx.y;
#pragma unroll
  for (int i = 0; i < 32; i += 8)
    tile[ty + i][tx] = X[(size_t)(m0 + ty + i) * NIN + k0 + tx];
  __syncthreads();
#pragma unroll
  for (int i = 0; i < 32; i += 8)
    Xt[(size_t)(k0 + ty + i) * MROWS + m0 + tx] = tile[tx][ty + i];
}

// ---------------------------------------------------------------- kernel 1
__global__ __launch_bounds__(256) void wt_convert(const float* __restrict__ W,
                                                  __hip_bfloat16* __restrict__ Wt) {
  __shared__ float tile[32][33];
  const int k0 = blockIdx.y << 5, n0 = blockIdx.x << 5;
  const int tx = threadIdx.x, ty = threadIdx.y;
#pragma unroll
  for (int i = 0; i < 32; i += 8)
    tile[ty + i][tx] = W[(size_t)(k0 + ty + i) * NN + n0 + tx];
  __syncthreads();
#pragma unroll
  for (int i = 0; i < 32; i += 8)
    Wt[(size_t)(n0 + ty + i) * NN + k0 + tx] = __float2bfloat16(tile[tx][ty + i]);
}

// ---------------------------------------------------------------- kernel 2
// fp32 GEMM: I[8192][2048] = Xt^T @ Wi + bias.
// 256x128 block tile, 256 threads, 16x8 micro-tile (cols split 4+4, 64 apart),
// BK=16. Both operands staged with global_load_lds width=16 into linear LDS.
// LDS reads: a = 4x b128 broadcast/2-way (free), b = 2x b128 2-way (free).
__global__ __launch_bounds__(256, 2) void in_gemm(const float* __restrict__ Xt,
                                                  const float* __restrict__ Wi,
                                                  const float* __restrict__ bias,
                                                  float* __restrict__ I) {
  __shared__ __align__(16) float As[16 * 256];  // [k][m] 16 KB
  __shared__ __align__(16) float Bs[16 * 128];  // [k][n] 8 KB
  const int tid = threadIdx.x;
  const int lane = tid & 63;
  const int w = tid >> 6;
  const int tm = tid >> 4;   // 0..15 -> 16-row strip
  const int tn = tid & 15;   // 0..15 -> cols {tn*4..+3} u {64+tn*4..+3}
  const int m0 = blockIdx.x * 256, n0 = blockIdx.y * 128;

  fx4 acc[16][2] = {};

  // staging pointers
  // A: row (k) = w*4+i, m-span = lane*4..+3  -> LDS off = (w*4+i)*1024 + lane*16
  const char* gA = (const char*)(Xt + (size_t)(w * 4) * MROWS + m0 + lane * 4);
  char* lA = (char*)As + w * 4096 + lane * 16;
  // B: row (k) = w*4 + j*2 + (lane>>5), n-span = (lane&31)*4..+3
  const char* gB = (const char*)(Wi + (size_t)(w * 4 + (lane >> 5)) * NN + n0 + (lane & 31) * 4);
  char* lB = (char*)Bs + w * 2048 + lane * 16;

  for (int k0 = 0; k0 < NIN; k0 += 16) {
#pragma unroll
    for (int i = 0; i < 4; ++i) gll16(gA + (size_t)i * (MROWS * 4), lA + i * 1024);
#pragma unroll
    for (int j = 0; j < 2; ++j) gll16(gB + (size_t)j * (2 * NN * 4), lB + j * 1024);
    gA += (size_t)16 * MROWS * 4;
    gB += (size_t)16 * NN * 4;
    __syncthreads();  // drains vmcnt+lgkmcnt
#pragma unroll
    for (int kk = 0; kk < 16; ++kk) {
      fx4 av[4], bv[2];
#pragma unroll
      for (int q = 0; q < 4; ++q) av[q] = *(const fx4*)&As[kk * 256 + tm * 16 + q * 4];
      bv[0] = *(const fx4*)&Bs[kk * 128 + tn * 4];
      bv[1] = *(const fx4*)&Bs[kk * 128 + 64 + tn * 4];
#pragma unroll
      for (int r = 0; r < 16; ++r) {
        const float a = av[r >> 2][r & 3];
#pragma unroll
        for (int j = 0; j < 2; ++j)
#pragma unroll
          for (int c = 0; c < 4; ++c)
            acc[r][j][c] = fmaf(a, bv[j][c], acc[r][j][c]);
      }
    }
    __syncthreads();
  }

#pragma unroll
  for (int r = 0; r < 16; ++r) {
    const size_t row = (size_t)(m0 + tm * 16 + r) * NN;
    fx4 r0, r1;
#pragma unroll
    for (int c = 0; c < 4; ++c) {
      r0[c] = acc[r][0][c] + bias[n0 + tn * 4 + c];
      r1[c] = acc[r][1][c] + bias[n0 + 64 + tn * 4 + c];
    }
    *(fx4*)&I[row + n0 + tn * 4] = r0;
    *(fx4*)&I[row + n0 + 64 + tn * 4] = r1;
  }
}

// ---------------------------------------------------------------- kernel 3
// Per-neuron serial scan over t. One thread per (b,n). Prefetch-unrolled x8.
// Matches numpy elementwise semantics: decay*v computed with separate
// mul+add (no fma contraction) so rounding matches the reference closely.
__device__ __forceinline__ void scan_body(float* zs, float* vsout,
                                          const float* I, __hip_bfloat16* Zb) {
  const int nid = blockIdx.x * 256 + threadIdx.x;  // 0..65535
  float v = 0.f;
  for (int t0 = 0; t0 < T_STEPS; t0 += 8) {
    float iin[8];
#pragma unroll
    for (int u = 0; u < 8; ++u)
      iin[u] = I[(size_t)(t0 + u) * BN_FLAT + nid];
#pragma unroll
    for (int u = 0; u < 8; ++u) {
      float nv = __fadd_rn(__fmul_rn(0.9048374180359595f, v), iin[u]);
      nv = fminf(fmaxf(nv, -1.0f), 1.01f);
      const bool sp = nv > 1.0f;        // == (new_v - THR) > 0 in fp32
      const float z = sp ? 1.0f : 0.0f;
      nv = sp ? -1.0f : nv;             // hard reset
      const size_t off = (size_t)(t0 + u) * BN_FLAT + nid;
      zs[off] = z;
      vsout[off] = nv;
      Zb[off] = __float2bfloat16(z);    // exact 0/1
      v = nv;
    }
  }
}

__global__ __launch_bounds__(256) void scan_sep(float* __restrict__ out,
                                                const float* __restrict__ I,
                                                __hip_bfloat16* __restrict__ Zb) {
  scan_body(out, out + (size_t)TBN, I, Zb);
}

__global__ __launch_bounds__(256) void scan_inp(float* out, __hip_bfloat16* Zb) {
  scan_body(out, out + (size_t)TBN, out + (size_t)TBN, Zb);  // I staged in vs region
}

// ---------------------------------------------------------------- kernel 4
// bf16 MFMA GEMM (m97 structure): Y[8192][2048] = Z[8192][2048] @ W[2048][2048]
// A = Z row-major bf16; B = Wt (W transposed) row-major bf16 so B-fragments
// are contiguous. 128x128 tile, BK=32, 4 waves (2x2), 16x16x32 MFMA.
__global__ __launch_bounds__(256) void bern_gemm(const __hip_bfloat16* __restrict__ Z,
                                                 const __hip_bfloat16* __restrict__ Wt,
                                                 float* __restrict__ Y) {
  __shared__ __align__(16) __hip_bfloat16 Asm[128 * 32];
  __shared__ __align__(16) __hip_bfloat16 Bsm[128 * 32];
  const int tid = threadIdx.x;
  const int lane = tid & 63;
  const int wid = tid >> 6;
  const int wr = wid >> 1, wc = wid & 1;
  const int m0 = blockIdx.x * 128, n0 = blockIdx.y * 128;

  fx4 acc[4][4] = {};

  const int trow = tid >> 2;
  const int tcol = (tid & 3) << 4;
  const char* gA = (const char*)Z + ((size_t)(m0 + trow) << 12) + tcol;
  const char* gB = (const char*)Wt + ((size_t)(n0 + trow) << 12) + tcol;
  char* lA = (char*)Asm + tid * 16;
  char* lB = (char*)Bsm + tid * 16;

  const ix4* Au = (const ix4*)Asm;  // 16B units; row = 4 units
  const ix4* Bu = (const ix4*)Bsm;
  const int abase = (wr * 64 + (lane & 15)) * 4 + (lane >> 4);
  const int bbase = (wc * 64 + (lane & 15)) * 4 + (lane >> 4);

  for (int ks = 0; ks < 64; ++ks) {
    gll16(gA, lA);
    gll16(gA + (size_t)64 * 4096, lA + 4096);
    gll16(gB, lB);
    gll16(gB + (size_t)64 * 4096, lB + 4096);
    gA += 64;  // advance 32 bf16 in k
    gB += 64;
    __syncthreads();

    ix4 af[4], bf[4];
#pragma unroll
    for (int i = 0; i < 4; ++i) af[i] = Au[abase + i * 64];
#pragma unroll
    for (int i = 0; i < 4; ++i) bf[i] = Bu[bbase + i * 64];
#pragma unroll
    for (int mf = 0; mf < 4; ++mf)
#pragma unroll
      for (int nf = 0; nf < 4; ++nf)
        mfma16(acc[mf][nf], af[mf], bf[nf]);
    __syncthreads();
  }

  asm volatile("s_nop 7\n\ts_nop 7");

  // C/D layout: col = lane&15, row = (lane>>4)*4 + reg  (m89-verified)
  const int crow = (lane >> 4) * 4;
  const int ccol = lane & 15;
#pragma unroll
  for (int mf = 0; mf < 4; ++mf)
#pragma unroll
    for (int nf = 0; nf < 4; ++nf)
#pragma unroll
      for (int j = 0; j < 4; ++j) {
        const int r = m0 + wr * 64 + mf * 16 + crow + j;
        const int c = n0 + wc * 64 + nf * 16 + ccol;
        Y[(size_t)r * NN + c] = acc[mf][nf][j];
      }
}

// ---------------------------------------------------------------- kernel 5
__global__ __launch_bounds__(256) void gather_k(float* __restrict__ Y,
                                                const int* __restrict__ ridx) {
  __shared__ __align__(16) float rowbuf[NN];
  const int tb = blockIdx.x;      // 0..8191
  const int t = tb >> 5;
  float* yrow = Y + (size_t)tb * NN;
  const int tid = threadIdx.x;
#pragma unroll
  for (int i = 0; i < 2; ++i) {
    int u = tid + i * 256;
    ((fx4*)rowbuf)[u] = ((const fx4*)yrow)[u];
  }
  __syncthreads();
  const int* ir = ridx + t * NN;
#pragma unroll
  for (int i = 0; i < 8; ++i) {
    int j = tid + i * 256;
    yrow[j] = rowbuf[ir[j]];
  }
}

// ---------------------------------------------------------------- launcher
extern "C" void kernel_launch(void* const* d_in, const int* in_sizes, int n_in,
                              void* d_out, int out_size, void* d_ws, size_t ws_size,
                              hipStream_t stream) {
  const float* x      = (const float*)d_in[0];
  const float* W_in   = (const float*)d_in[1];
  const float* bias   = (const float*)d_in[2];
  const float* W_bern = (const float*)d_in[3];
  const int*   ridx   = (const int*)d_in[4];
  float* out = (float*)d_out;
  char* ws = (char*)d_ws;

  __hip_bfloat16* Wt = (__hip_bfloat16*)ws;                       // 8,388,608 B
  __hip_bfloat16* Zb = (__hip_bfloat16*)(ws + (size_t)8388608);   // 33,554,432 B
  const size_t offI = 41943040;                                   // I: 67,108,864 B
  const bool sep = ws_size >= (size_t)109051904;
  float* Ibuf = sep ? (float*)(ws + offI) : (out + (size_t)TBN);

  // Xt borrows the zs output region (2M floats); scan overwrites it later.
  float* Xt = out;

  xt_k<<<dim3(256, 8), dim3(32, 8), 0, stream>>>(x, Xt);
  wt_convert<<<dim3(64, 64), dim3(32, 8), 0, stream>>>(W_bern, Wt);
  in_gemm<<<dim3(32, 16), dim3(256), 0, stream>>>(Xt, W_in, bias, Ibuf);
  if (sep)
    scan_sep<<<dim3(256), dim3(256), 0, stream>>>(out, Ibuf, Zb);
  else
    scan_inp<<<dim3(256), dim3(256), 0, stream>>>(out, Zb);
  bern_gemm<<<dim3(64, 16), dim3(256), 0, stream>>>(Zb, Wt, out + (size_t)2 * TBN);
  gather_k<<<dim3(8192), dim3(256), 0, stream>>>(out + (size_t)2 * TBN, ridx);
}